// Round 1
// baseline (285.008 us; speedup 1.0000x reference)
//
#include <hip/hip_runtime.h>
#include <hip/hip_fp16.h>
#include <cstdint>

constexpr int BSHIFT = 9;               // 512 nodes per bucket
constexpr int NBUCK  = 256;             // max buckets (covers 131072 nodes)
constexpr int BUCKET_CAP = 6144;        // slot capacity; E/bucket ~ Poisson(5102), 14 sigma

struct alignas(16) H8 { __half2 a, b, c, d; };
struct alignas(8)  H4 { __half2 a, b; };

__device__ __forceinline__ float4 add4(float4 a, float4 b) {
    return make_float4(a.x + b.x, a.y + b.y, a.z + b.z, a.w + b.w);
}
__device__ __forceinline__ float4 mul4s(float4 a, float s) {
    return make_float4(a.x * s, a.y * s, a.z * s, a.w * s);
}
__device__ __forceinline__ void acc_h8(float4& A0, float4& A1, const H8 v, float s) {
    float2 f0 = __half22float2(v.a), f1 = __half22float2(v.b);
    float2 f2 = __half22float2(v.c), f3 = __half22float2(v.d);
    A0.x = fmaf(f0.x, s, A0.x); A0.y = fmaf(f0.y, s, A0.y);
    A0.z = fmaf(f1.x, s, A0.z); A0.w = fmaf(f1.y, s, A0.w);
    A1.x = fmaf(f2.x, s, A1.x); A1.y = fmaf(f2.y, s, A1.y);
    A1.z = fmaf(f3.x, s, A1.z); A1.w = fmaf(f3.y, s, A1.w);
}

// ---------------- CSR build (R12-proven: LDS-local bucket_csr) ----------------

constexpr int EPT = 16;  // edges per thread; chunk = 4096
__global__ __launch_bounds__(256) void partition_edges(
    const int* __restrict__ src, const int* __restrict__ dst,
    int* __restrict__ bucketCur, int* __restrict__ pairs, int ne) {
    __shared__ int lcnt[NBUCK];
    __shared__ int lbase[NBUCK];
    int base = blockIdx.x * (256 * EPT);
    if (threadIdx.x < NBUCK) lcnt[threadIdx.x] = 0;
    __syncthreads();
    int2 ed[EPT];
    int  rnk[EPT];
#pragma unroll
    for (int j = 0; j < EPT; ++j) {
        int e = base + j * 256 + threadIdx.x;
        if (e < ne) {
            int d = dst[e];
            ed[j] = make_int2(src[e], d);
            rnk[j] = atomicAdd(&lcnt[d >> BSHIFT], 1);
        } else {
            ed[j].y = -1;
        }
    }
    __syncthreads();
    if (threadIdx.x < NBUCK) {
        int c = lcnt[threadIdx.x];
        lbase[threadIdx.x] = c ? atomicAdd(&bucketCur[threadIdx.x], c) : 0;
    }
    __syncthreads();
#pragma unroll
    for (int j = 0; j < EPT; ++j) {
        if (ed[j].y >= 0) {
            int b = ed[j].y >> BSHIFT;
            int p = lbase[b] + rnk[j];
            if (p < BUCKET_CAP)
                pairs[(size_t)b * BUCKET_CAP + p] =
                    (ed[j].x << BSHIFT) | (ed[j].y & ((1 << BSHIFT) - 1));
        }
    }
}

__global__ void scan_buckets(const int* __restrict__ bucketCnt, int* __restrict__ bucketBase,
                             int* __restrict__ offs, int n, int ne, int nbuckets) {
    __shared__ int tmp[256];
    int c = (threadIdx.x < (unsigned)nbuckets) ? bucketCnt[threadIdx.x] : 0;
    tmp[threadIdx.x] = c;
    __syncthreads();
    for (int off = 1; off < 256; off <<= 1) {
        int t = (threadIdx.x >= (unsigned)off) ? tmp[threadIdx.x - off] : 0;
        __syncthreads();
        tmp[threadIdx.x] += t;
        __syncthreads();
    }
    if (threadIdx.x < (unsigned)nbuckets) bucketBase[threadIdx.x] = tmp[threadIdx.x] - c;
    if (threadIdx.x == 0) offs[n] = ne;
}

__global__ __launch_bounds__(256) void bucket_csr(
    const int* __restrict__ pairs, const int* __restrict__ bucketCnt,
    const int* __restrict__ bucketBase, int* __restrict__ offs,
    float* __restrict__ dinv, int* __restrict__ csr, int n) {
    constexpr int BN = 1 << BSHIFT;  // 512
    __shared__ int hist[BN];
    __shared__ int cur[BN];
    __shared__ int tmp[256];
    int b = blockIdx.x;
    int cnt  = bucketCnt[b];
    int base = bucketBase[b];
    const int* pb = pairs + (size_t)b * BUCKET_CAP;
    int nodeLo = b << BSHIFT;

    hist[threadIdx.x] = 0;
    hist[threadIdx.x + 256] = 0;
    __syncthreads();
    for (int e = threadIdx.x; e < cnt; e += 256)
        atomicAdd(&hist[pb[e] & (BN - 1)], 1);
    __syncthreads();

    int l0 = 2 * threadIdx.x, l1 = l0 + 1;
    int h0 = hist[l0], h1 = hist[l1];
    tmp[threadIdx.x] = h0 + h1;
    __syncthreads();
    for (int off = 1; off < 256; off <<= 1) {
        int t = (threadIdx.x >= (unsigned)off) ? tmp[threadIdx.x - off] : 0;
        __syncthreads();
        tmp[threadIdx.x] += t;
        __syncthreads();
    }
    int e0 = tmp[threadIdx.x] - (h0 + h1);
    int e1 = e0 + h0;
    int g0 = nodeLo + l0, g1 = nodeLo + l1;
    if (g0 < n) { offs[g0] = base + e0; dinv[g0] = rsqrtf((float)(h0 + 1)); }
    if (g1 < n) { offs[g1] = base + e1; dinv[g1] = rsqrtf((float)(h1 + 1)); }
    cur[l0] = e0;
    cur[l1] = e1;
    __syncthreads();

    for (int e = threadIdx.x; e < cnt; e += 256) {
        int p = pb[e];
        int pos = atomicAdd(&cur[p & (BN - 1)], 1);
        csr[base + pos] = ((unsigned)p) >> BSHIFT;
    }
}

// ---------------- fp32 -> fp16 streaming convert, prescaled by dinv ----------------
// y[i] = fp16(dinv[node] * x[i]); lets agg1 drop the per-edge dinv gather.
__global__ void cvt_scale_f32_f16(const float* __restrict__ x, const float* __restrict__ dinv,
                                  __half* __restrict__ o, int n4) {
    int i = blockIdx.x * blockDim.x + threadIdx.x;
    if (i < n4) {
        float dv = dinv[i >> 4];          // 16 float4 per 64-wide row
        float4 v = ((const float4*)x)[i];
        H4 h;
        h.a = __floats2half2_rn(v.x * dv, v.y * dv);
        h.b = __floats2half2_rn(v.z * dv, v.w * dv);
        ((H4*)o)[i] = h;
    }
}

// ---------------- agg1: fp16 gather (K=64), rows pre-scaled by dinv[src] ----------------
__global__ __launch_bounds__(256) void agg1_h(
    const __half* __restrict__ s, const int* __restrict__ offs,
    const int* __restrict__ csr, const float* __restrict__ dinv,
    __half* __restrict__ out, int n) {
    int lane = threadIdx.x & 7;
    int node = blockIdx.x * 32 + (threadIdx.x >> 3);
    if (node >= n) return;
    int f0 = lane * 8;
    float dv = dinv[node];

    float4 z = make_float4(0.f, 0.f, 0.f, 0.f);
    float4 a00 = z, a01 = z, a10 = z, a11 = z, a20 = z, a21 = z, a30 = z, a31 = z;
    {
        H8 sv = *(const H8*)&s[(size_t)node * 64 + f0];   // y[node] = dinv*x -> self term
        acc_h8(a00, a01, sv, 1.0f);
    }
    int e0 = offs[node], e1 = offs[node + 1];
    int e = e0;
    for (; e + 4 <= e1; e += 4) {
        int i0 = csr[e], i1 = csr[e + 1], i2 = csr[e + 2], i3 = csr[e + 3];
        H8 v0 = *(const H8*)&s[(size_t)i0 * 64 + f0];
        H8 v1 = *(const H8*)&s[(size_t)i1 * 64 + f0];
        H8 v2 = *(const H8*)&s[(size_t)i2 * 64 + f0];
        H8 v3 = *(const H8*)&s[(size_t)i3 * 64 + f0];
        acc_h8(a00, a01, v0, 1.0f);
        acc_h8(a10, a11, v1, 1.0f);
        acc_h8(a20, a21, v2, 1.0f);
        acc_h8(a30, a31, v3, 1.0f);
    }
    for (; e < e1; ++e) {
        int sid = csr[e];
        H8 v = *(const H8*)&s[(size_t)sid * 64 + f0];
        acc_h8(a00, a01, v, 1.0f);
    }
    float4 A0 = add4(add4(a00, a10), add4(a20, a30));
    float4 A1 = add4(add4(a01, a11), add4(a21, a31));
    A0 = mul4s(A0, dv);
    A1 = mul4s(A1, dv);

    H8 h;
    h.a = __floats2half2_rn(A0.x, A0.y);
    h.b = __floats2half2_rn(A0.z, A0.w);
    h.c = __floats2half2_rn(A1.x, A1.y);
    h.d = __floats2half2_rn(A1.z, A1.w);
    *(H8*)&out[(size_t)node * 64 + f0] = h;
}

// ---------------- agg2: fp16 gather (M=50 in s64h rows), fp16 out (zero-padded) ---------
__global__ __launch_bounds__(256) void agg2_h16(
    const __half* __restrict__ s, const int* __restrict__ offs,
    const int* __restrict__ csr, const float* __restrict__ dinv,
    const float* __restrict__ b, __half* __restrict__ out, int n) {
    constexpr int MH = 50, SH = 64;
    int lane = threadIdx.x & 7;
    int node = blockIdx.x * 32 + (threadIdx.x >> 3);
    if (node >= n) return;
    int f0 = lane * 8;
    H8 zh{};
    if (f0 >= 56) {              // lane 7: pure zero-pad (halves 56..63)
        *(H8*)&out[(size_t)node * SH + f0] = zh;
        return;
    }
    float dv = dinv[node];

    float4 z = make_float4(0.f, 0.f, 0.f, 0.f);
    float4 a00 = z, a01 = z, a10 = z, a11 = z, a20 = z, a21 = z, a30 = z, a31 = z;
    {
        H8 sv = *(const H8*)&s[(size_t)node * SH + f0];
        acc_h8(a00, a01, sv, 1.0f);
    }
    int e0 = offs[node], e1 = offs[node + 1];
    int e = e0;
    for (; e + 4 <= e1; e += 4) {
        int i0 = csr[e], i1 = csr[e + 1], i2 = csr[e + 2], i3 = csr[e + 3];
        H8 v0 = *(const H8*)&s[(size_t)i0 * SH + f0];
        H8 v1 = *(const H8*)&s[(size_t)i1 * SH + f0];
        H8 v2 = *(const H8*)&s[(size_t)i2 * SH + f0];
        H8 v3 = *(const H8*)&s[(size_t)i3 * SH + f0];
        acc_h8(a00, a01, v0, 1.0f);
        acc_h8(a10, a11, v1, 1.0f);
        acc_h8(a20, a21, v2, 1.0f);
        acc_h8(a30, a31, v3, 1.0f);
    }
    for (; e < e1; ++e) {
        H8 v = *(const H8*)&s[(size_t)csr[e] * SH + f0];
        acc_h8(a00, a01, v, 1.0f);
    }
    float4 A0 = add4(add4(a00, a10), add4(a20, a30));
    float4 A1 = add4(add4(a01, a11), add4(a21, a31));
    float v[8] = {A0.x, A0.y, A0.z, A0.w, A1.x, A1.y, A1.z, A1.w};
#pragma unroll
    for (int i = 0; i < 8; ++i)
        v[i] = (f0 + i < MH) ? fmaxf(dv * v[i] + b[f0 + i], 0.0f) : 0.0f;
    H8 h;
    h.a = __floats2half2_rn(v[0], v[1]);
    h.b = __floats2half2_rn(v[2], v[3]);
    h.c = __floats2half2_rn(v[4], v[5]);
    h.d = __floats2half2_rn(v[6], v[7]);
    *(H8*)&out[(size_t)node * SH + f0] = h;
}

// ---------------- fused gemm1+gemm2: bufDh = dinv * (relu(bufAh@W1+b1) @ W2) ----------------
// Intermediate H (100-wide) lives in LDS; kills the 44.8MB bufBh HBM round-trip.
// Weights staged to LDS as fp16 to stay under 64KB static LDS (52.5KB total -> 3 blocks/CU).
constexpr int G12_NT = 40;
__global__ __launch_bounds__(256) void gemm12_fused(
    const __half* __restrict__ x, const float* __restrict__ W1, const float* __restrict__ b1,
    const float* __restrict__ W2, const float* __restrict__ dinv,
    __half* __restrict__ out, int n) {
    constexpr int K1 = 64, M1 = 100, M2 = 50, M2p = 52, XS = 64, OS = 64;
    constexpr int NT = G12_NT, NTp = NT + 4;

    __shared__ float  Xs[K1 * NTp];     // 11.3 KB
    __shared__ float  Hs[M1 * NTp];     // 17.6 KB
    __shared__ __half W1h[K1 * M1];     // 12.8 KB
    __shared__ __half W2h[M1 * M2p];    // 10.4 KB (cols 50,51 zero)
    __shared__ float  b1s[M1];

    // stage W1 (f32 -> fp16, float4 granularity; 64*100 % 4 == 0)
    for (int i = threadIdx.x; i < K1 * M1 / 4; i += 256) {
        float4 v = ((const float4*)W1)[i];
        H4 h;
        h.a = __floats2half2_rn(v.x, v.y);
        h.b = __floats2half2_rn(v.z, v.w);
        ((H4*)W1h)[i] = h;
    }
    // stage W2 (100x50 -> 100x52 padded, float2 granularity)
    {
        constexpr int C2 = M2p / 2;     // 26
        for (int i = threadIdx.x; i < M1 * C2; i += 256) {
            int r = i / C2, c = i - r * C2;
            float2 v = make_float2(0.0f, 0.0f);
            if (c * 2 + 1 < M2) v = *(const float2*)&W2[r * M2 + c * 2];
            *(__half2*)&W2h[r * M2p + c * 2] = __floats2half2_rn(v.x, v.y);
        }
    }
    for (int i = threadIdx.x; i < M1; i += 256) b1s[i] = b1[i];

    // stage X tile [K1 x NT] (transposed, fp32 in LDS)
    int nodeBase = blockIdx.x * NT;
    for (int it = threadIdx.x; it < NT * (K1 / 8); it += 256) {
        int node = it % NT;
        int kv = it / NT;
        int gn = nodeBase + node;
        H8 h{};
        if (gn < n) h = *(const H8*)&x[(size_t)gn * XS + kv * 8];
        float2 f0_ = __half22float2(h.a), f1_ = __half22float2(h.b);
        float2 f2_ = __half22float2(h.c), f3_ = __half22float2(h.d);
        Xs[(kv * 8 + 0) * NTp + node] = f0_.x;
        Xs[(kv * 8 + 1) * NTp + node] = f0_.y;
        Xs[(kv * 8 + 2) * NTp + node] = f1_.x;
        Xs[(kv * 8 + 3) * NTp + node] = f1_.y;
        Xs[(kv * 8 + 4) * NTp + node] = f2_.x;
        Xs[(kv * 8 + 5) * NTp + node] = f2_.y;
        Xs[(kv * 8 + 6) * NTp + node] = f3_.x;
        Xs[(kv * 8 + 7) * NTp + node] = f3_.y;
    }
    __syncthreads();

    // phase B: H = relu(X@W1 + b1), 250 active threads, 4x4 tiles
    {
        constexpr int MQ1 = M1 / 4;     // 25
        int t = threadIdx.x;
        if (t < (NT / 4) * MQ1) {
            int ng = t / MQ1, mq = t - ng * MQ1;
            int n0 = ng * 4, m0 = mq * 4;
            float acc[4][4] = {};
#pragma unroll 4
            for (int k = 0; k < K1; ++k) {
                float4 xv = *(const float4*)&Xs[k * NTp + n0];
                H4 wh = *(const H4*)&W1h[k * M1 + m0];
                float2 w01 = __half22float2(wh.a), w23 = __half22float2(wh.b);
                acc[0][0] = fmaf(xv.x, w01.x, acc[0][0]); acc[0][1] = fmaf(xv.x, w01.y, acc[0][1]);
                acc[0][2] = fmaf(xv.x, w23.x, acc[0][2]); acc[0][3] = fmaf(xv.x, w23.y, acc[0][3]);
                acc[1][0] = fmaf(xv.y, w01.x, acc[1][0]); acc[1][1] = fmaf(xv.y, w01.y, acc[1][1]);
                acc[1][2] = fmaf(xv.y, w23.x, acc[1][2]); acc[1][3] = fmaf(xv.y, w23.y, acc[1][3]);
                acc[2][0] = fmaf(xv.z, w01.x, acc[2][0]); acc[2][1] = fmaf(xv.z, w01.y, acc[2][1]);
                acc[2][2] = fmaf(xv.z, w23.x, acc[2][2]); acc[2][3] = fmaf(xv.z, w23.y, acc[2][3]);
                acc[3][0] = fmaf(xv.w, w01.x, acc[3][0]); acc[3][1] = fmaf(xv.w, w01.y, acc[3][1]);
                acc[3][2] = fmaf(xv.w, w23.x, acc[3][2]); acc[3][3] = fmaf(xv.w, w23.y, acc[3][3]);
            }
#pragma unroll
            for (int i = 0; i < 4; ++i) {
                float bb = b1s[m0 + i];
#pragma unroll
                for (int j = 0; j < 4; ++j)
                    Hs[(m0 + i) * NTp + (n0 + j)] = fmaxf(acc[j][i] + bb, 0.0f);
            }
        }
    }
    __syncthreads();

    // phase C: out = (H@W2) * dinv, 130 active threads, 4x4 tiles
    {
        constexpr int MQ2 = M2p / 4;    // 13
        int t = threadIdx.x;
        if (t >= (NT / 4) * MQ2) return;
        int ng = t / MQ2, mq = t - ng * MQ2;
        int n0 = ng * 4, m0 = mq * 4;
        float acc[4][4] = {};
#pragma unroll 4
        for (int k = 0; k < M1; ++k) {
            float4 xv = *(const float4*)&Hs[k * NTp + n0];
            H4 wh = *(const H4*)&W2h[k * M2p + m0];
            float2 w01 = __half22float2(wh.a), w23 = __half22float2(wh.b);
            acc[0][0] = fmaf(xv.x, w01.x, acc[0][0]); acc[0][1] = fmaf(xv.x, w01.y, acc[0][1]);
            acc[0][2] = fmaf(xv.x, w23.x, acc[0][2]); acc[0][3] = fmaf(xv.x, w23.y, acc[0][3]);
            acc[1][0] = fmaf(xv.y, w01.x, acc[1][0]); acc[1][1] = fmaf(xv.y, w01.y, acc[1][1]);
            acc[1][2] = fmaf(xv.y, w23.x, acc[1][2]); acc[1][3] = fmaf(xv.y, w23.y, acc[1][3]);
            acc[2][0] = fmaf(xv.z, w01.x, acc[2][0]); acc[2][1] = fmaf(xv.z, w01.y, acc[2][1]);
            acc[2][2] = fmaf(xv.z, w23.x, acc[2][2]); acc[2][3] = fmaf(xv.z, w23.y, acc[2][3]);
            acc[3][0] = fmaf(xv.w, w01.x, acc[3][0]); acc[3][1] = fmaf(xv.w, w01.y, acc[3][1]);
            acc[3][2] = fmaf(xv.w, w23.x, acc[3][2]); acc[3][3] = fmaf(xv.w, w23.y, acc[3][3]);
        }
#pragma unroll
        for (int j = 0; j < 4; ++j) {
            int nd = nodeBase + n0 + j;
            if (nd >= n) continue;
            float dv = dinv[nd];
            H4 h;
            h.a = __floats2half2_rn(acc[j][0] * dv, acc[j][1] * dv);
            h.b = __floats2half2_rn(acc[j][2] * dv, acc[j][3] * dv);
            *(H4*)&out[(size_t)nd * OS + m0] = h;   // cols 50,51 are zeros (padded W2)
        }
    }
}

// ---------------- register-tiled GEMM (still used for gemm3) ----------------
template <int K, int M, int NT, int XS, int OS, bool SCALE, bool BIAS_RELU, int KR>
__global__ __launch_bounds__(256) void gemm_tiled_h(
    const __half* __restrict__ x, const float* __restrict__ W,
    const float* __restrict__ dinv, const float* __restrict__ b,
    __half* __restrict__ out, int n) {
    static_assert(NT % 4 == 0 && K % 4 == 0 && OS % 4 == 0, "");
    constexpr int Mp  = (M + 3) & ~3;
    constexpr int MQ  = Mp / 4;
    constexpr int NTp = NT + 4;
    constexpr int NTILES = (NT / 4) * MQ;
    static_assert(NTILES <= 256, "");
    static_assert(M % 4 != 0 || KR == K, "float4 W path assumes KR==K");

    __shared__ float Xs[K * NTp];
    __shared__ float Ws[K * Mp];

    if constexpr (M % 4 == 0) {
        for (int i = threadIdx.x; i < K * M / 4; i += 256)
            ((float4*)Ws)[i] = ((const float4*)W)[i];
    } else if constexpr (M % 2 == 0) {
        constexpr int C2 = Mp / 2;
        for (int i = threadIdx.x; i < K * C2; i += 256) {
            int r = i / C2, c = i - r * C2;
            float2 v = make_float2(0.0f, 0.0f);
            if (r < KR) {
                if (c * 2 + 1 < M)  v = *(const float2*)&W[r * M + c * 2];
                else if (c * 2 < M) v = make_float2(W[r * M + c * 2], 0.0f);
            }
            *(float2*)&Ws[r * Mp + c * 2] = v;
        }
    } else {
        for (int i = threadIdx.x; i < K * Mp; i += 256) {
            int r = i / Mp, c = i - r * Mp;
            Ws[i] = (c < M && r < KR) ? W[r * M + c] : 0.0f;
        }
    }

    int nodeBase = blockIdx.x * NT;
    constexpr int KVH = (K % 8 == 0) ? 8 : 4;
    for (int it = threadIdx.x; it < NT * (K / KVH); it += 256) {
        int node = it % NT;
        int kv = it / NT;
        int gn = nodeBase + node;
        if constexpr (KVH == 8) {
            H8 h{};
            if (gn < n) h = *(const H8*)&x[(size_t)gn * XS + kv * 8];
            float2 f0_ = __half22float2(h.a), f1_ = __half22float2(h.b);
            float2 f2_ = __half22float2(h.c), f3_ = __half22float2(h.d);
            Xs[(kv * 8 + 0) * NTp + node] = f0_.x;
            Xs[(kv * 8 + 1) * NTp + node] = f0_.y;
            Xs[(kv * 8 + 2) * NTp + node] = f1_.x;
            Xs[(kv * 8 + 3) * NTp + node] = f1_.y;
            Xs[(kv * 8 + 4) * NTp + node] = f2_.x;
            Xs[(kv * 8 + 5) * NTp + node] = f2_.y;
            Xs[(kv * 8 + 6) * NTp + node] = f3_.x;
            Xs[(kv * 8 + 7) * NTp + node] = f3_.y;
        } else {
            H4 h{};
            if (gn < n) h = *(const H4*)&x[(size_t)gn * XS + kv * 4];
            float2 f0_ = __half22float2(h.a), f1_ = __half22float2(h.b);
            Xs[(kv * 4 + 0) * NTp + node] = f0_.x;
            Xs[(kv * 4 + 1) * NTp + node] = f0_.y;
            Xs[(kv * 4 + 2) * NTp + node] = f1_.x;
            Xs[(kv * 4 + 3) * NTp + node] = f1_.y;
        }
    }
    __syncthreads();

    int t = threadIdx.x;
    if (t >= NTILES) return;
    int ng = t / MQ, mq = t - ng * MQ;
    int n0 = ng * 4;
    int m0 = mq * 4;

    float acc[4][4];
#pragma unroll
    for (int j = 0; j < 4; ++j)
#pragma unroll
        for (int i = 0; i < 4; ++i) acc[j][i] = 0.0f;

#pragma unroll 4
    for (int k = 0; k < K; ++k) {
        float4 xv = *(const float4*)&Xs[k * NTp + n0];
        float4 wv = *(const float4*)&Ws[k * Mp + m0];
        acc[0][0] = fmaf(xv.x, wv.x, acc[0][0]); acc[0][1] = fmaf(xv.x, wv.y, acc[0][1]);
        acc[0][2] = fmaf(xv.x, wv.z, acc[0][2]); acc[0][3] = fmaf(xv.x, wv.w, acc[0][3]);
        acc[1][0] = fmaf(xv.y, wv.x, acc[1][0]); acc[1][1] = fmaf(xv.y, wv.y, acc[1][1]);
        acc[1][2] = fmaf(xv.y, wv.z, acc[1][2]); acc[1][3] = fmaf(xv.y, wv.w, acc[1][3]);
        acc[2][0] = fmaf(xv.z, wv.x, acc[2][0]); acc[2][1] = fmaf(xv.z, wv.y, acc[2][1]);
        acc[2][2] = fmaf(xv.z, wv.z, acc[2][2]); acc[2][3] = fmaf(xv.z, wv.w, acc[2][3]);
        acc[3][0] = fmaf(xv.w, wv.x, acc[3][0]); acc[3][1] = fmaf(xv.w, wv.y, acc[3][1]);
        acc[3][2] = fmaf(xv.w, wv.z, acc[3][2]); acc[3][3] = fmaf(xv.w, wv.w, acc[3][3]);
    }

#pragma unroll
    for (int j = 0; j < 4; ++j) {
        int nd = nodeBase + n0 + j;
        if (nd >= n) continue;
        float dv = SCALE ? dinv[nd] : 1.0f;
        float r[4];
#pragma unroll
        for (int i = 0; i < 4; ++i) {
            r[i] = acc[j][i];
            if (SCALE) r[i] *= dv;
            if (BIAS_RELU) r[i] = fmaxf(r[i] + b[m0 + i], 0.0f);
        }
        if (m0 + 3 < M) {
            H4 h;
            h.a = __floats2half2_rn(r[0], r[1]);
            h.b = __floats2half2_rn(r[2], r[3]);
            *(H4*)&out[(size_t)nd * OS + m0] = h;
        } else {
#pragma unroll
            for (int i = 0; i < 4; ++i)
                if (m0 + i < M) out[(size_t)nd * OS + m0 + i] = __float2half_rn(r[i]);
        }
    }
}

// ---------------- agg3 (fp16 gather, 1 line/row) + MLP head ----------------
__global__ __launch_bounds__(256) void agg3_mlp_h(
    const __half* __restrict__ s, const int* __restrict__ offs,
    const int* __restrict__ csr, const float* __restrict__ dinv,
    const float* __restrict__ bg,
    const float* __restrict__ Wl1, const float* __restrict__ bl1,
    const float* __restrict__ Wl2, const float* __restrict__ bl2,
    const float* __restrict__ Wl3, const float* __restrict__ bl3,
    float* __restrict__ out, int n) {
    constexpr int MH = 25, SH = 32, LPN = 4;
    __shared__ float W1s[625], W2s[250], W3s[10], b1s[25], b2s[10];
    __shared__ float accs[64 * 26];
    __shared__ float b3s;

    for (int i = threadIdx.x; i < 625; i += 256) W1s[i] = Wl1[i];
    for (int i = threadIdx.x; i < 250; i += 256) W2s[i] = Wl2[i];
    if (threadIdx.x < 10) { W3s[threadIdx.x] = Wl3[threadIdx.x]; b2s[threadIdx.x] = bl2[threadIdx.x]; }
    if (threadIdx.x < 25) b1s[threadIdx.x] = bl1[threadIdx.x];
    if (threadIdx.x == 0) b3s = bl3[0];

    int lane = threadIdx.x % LPN;
    int nl   = threadIdx.x / LPN;
    int node = blockIdx.x * 64 + nl;
    int f0 = lane * 8;

    if (node < n && f0 < MH) {
        float dv = dinv[node];
        float4 z = make_float4(0.f, 0.f, 0.f, 0.f);
        float4 a00 = z, a01 = z, a10 = z, a11 = z, a20 = z, a21 = z, a30 = z, a31 = z;
        {
            H8 sv = *(const H8*)&s[(size_t)node * SH + f0];
            acc_h8(a00, a01, sv, 1.0f);
        }
        int e0 = offs[node], e1 = offs[node + 1];
        int e = e0;
        for (; e + 4 <= e1; e += 4) {
            int i0 = csr[e], i1 = csr[e + 1], i2 = csr[e + 2], i3 = csr[e + 3];
            H8 v0 = *(const H8*)&s[(size_t)i0 * SH + f0];
            H8 v1 = *(const H8*)&s[(size_t)i1 * SH + f0];
            H8 v2 = *(const H8*)&s[(size_t)i2 * SH + f0];
            H8 v3 = *(const H8*)&s[(size_t)i3 * SH + f0];
            acc_h8(a00, a01, v0, 1.0f);
            acc_h8(a10, a11, v1, 1.0f);
            acc_h8(a20, a21, v2, 1.0f);
            acc_h8(a30, a31, v3, 1.0f);
        }
        for (; e < e1; ++e) {
            H8 v = *(const H8*)&s[(size_t)csr[e] * SH + f0];
            acc_h8(a00, a01, v, 1.0f);
        }
        float4 A0 = add4(add4(a00, a10), add4(a20, a30));
        float4 A1 = add4(add4(a01, a11), add4(a21, a31));
        float v[8] = {A0.x, A0.y, A0.z, A0.w, A1.x, A1.y, A1.z, A1.w};
#pragma unroll
        for (int i = 0; i < 8; ++i)
            if (f0 + i < MH)
                accs[nl * 26 + f0 + i] = fmaxf(dv * v[i] + bg[f0 + i], 0.0f);
    }
    __syncthreads();

    if (threadIdx.x < 64) {
        int nd = blockIdx.x * 64 + threadIdx.x;
        if (nd < n) {
            const float* xr = &accs[threadIdx.x * 26];
            float h1[25];
#pragma unroll
            for (int m = 0; m < 25; ++m) {
                float a = b1s[m];
#pragma unroll
                for (int k = 0; k < 25; ++k) a = fmaf(xr[k], W1s[k * 25 + m], a);
                h1[m] = fmaxf(a, 0.0f);
            }
            float h2[10];
#pragma unroll
            for (int m = 0; m < 10; ++m) {
                float a = b2s[m];
#pragma unroll
                for (int k = 0; k < 25; ++k) a = fmaf(h1[k], W2s[k * 10 + m], a);
                h2[m] = fmaxf(a, 0.0f);
            }
            float a = b3s;
#pragma unroll
            for (int k = 0; k < 10; ++k) a = fmaf(h2[k], W3s[k], a);
            out[nd] = fmaxf(a, 0.0f);
        }
    }
}

// ---------------- launch ----------------

extern "C" void kernel_launch(void* const* d_in, const int* in_sizes, int n_in,
                              void* d_out, int out_size, void* d_ws, size_t ws_size,
                              hipStream_t stream) {
    const float* x0  = (const float*)d_in[0];
    const float* W1  = (const float*)d_in[1];
    const float* b1  = (const float*)d_in[2];
    const float* W2  = (const float*)d_in[3];
    const float* b2  = (const float*)d_in[4];
    const float* W3  = (const float*)d_in[5];
    const float* b3  = (const float*)d_in[6];
    const float* Wl1 = (const float*)d_in[7];
    const float* bl1 = (const float*)d_in[8];
    const float* Wl2 = (const float*)d_in[9];
    const float* bl2 = (const float*)d_in[10];
    const float* Wl3 = (const float*)d_in[11];
    const float* bl3 = (const float*)d_in[12];
    const int*   edge = (const int*)d_in[13];

    int n  = in_sizes[0] / 64;      // 100000
    int ne = in_sizes[13] / 2;      // 1000000
    const int* esrc = edge;
    const int* edst = edge + ne;

    char* ws = (char*)d_ws;
    auto alloc = [&](size_t bytes) {
        char* p = ws;
        ws += (bytes + 255) & ~(size_t)255;
        return p;
    };
    int*    offs       = (int*)alloc((size_t)(n + 1) * 4);
    int*    bucketCur  = (int*)alloc(NBUCK * 4);
    int*    bucketBase = (int*)alloc(NBUCK * 4);
    int*    csr        = (int*)alloc((size_t)ne * 4);
    float*  dinv       = (float*)alloc((size_t)n * 4);
    __half* x0h        = (__half*)alloc((size_t)n * 64 * 2);   // fp16 s64h (cvt out, dinv-prescaled)
    __half* bufAh      = (__half*)alloc((size_t)n * 64 * 2);   // fp16 s64h (agg1 out)
    __half* bufDh      = (__half*)alloc((size_t)n * 64 * 2);   // fp16 s64h (gemm12 out)
    // aliases (ordered lifetimes):
    //   pairs (6.3MB) in bufDh: consumed by bucket_csr before gemm12 writes bufDh
    //   bufEh (agg2 out, s64h) aliases x0h (dead after agg1)
    //   bufCh (gemm3 out, s32h) aliases bufAh (dead after gemm12)
    int*    pairs = (int*)bufDh;
    __half* bufEh = x0h;
    __half* bufCh = bufAh;
    (void)ws_size; (void)n_in; (void)out_size;

    int nbuckets = (n + (1 << BSHIFT) - 1) >> BSHIFT;   // 196

    // CSR + dinv (memset + 3 dispatches; R12-proven LDS-local scatter)
    hipMemsetAsync(bucketCur, 0, NBUCK * 4, stream);
    partition_edges<<<(ne + 256 * EPT - 1) / (256 * EPT), 256, 0, stream>>>(
        esrc, edst, bucketCur, pairs, ne);
    scan_buckets<<<1, 256, 0, stream>>>(bucketCur, bucketBase, offs, n, ne, nbuckets);
    bucket_csr<<<nbuckets, 256, 0, stream>>>(pairs, bucketCur, bucketBase, offs, dinv, csr, n);

    // x0h = fp16(dinv * x0)  (prescale: agg1 no longer gathers dinv per edge)
    cvt_scale_f32_f16<<<(n * 16 + 255) / 256, 256, 0, stream>>>(x0, dinv, x0h, n * 16);

    // agg1: bufAh = fp16(ÂX)
    agg1_h<<<(n + 31) / 32, 256, 0, stream>>>(x0h, offs, csr, dinv, bufAh, n);

    // gemm12 fused: bufDh = fp16(dinv * (relu(bufAh@W1+b1) @ W2))  [K=64 -> 100 -> 50]
    gemm12_fused<<<(n + G12_NT - 1) / G12_NT, 256, 0, stream>>>(
        bufAh, W1, b1, W2, dinv, bufDh, n);

    // agg2: bufEh = fp16(relu(dinv*agg(bufDh)+b2)), zero-padded to 64h rows
    agg2_h16<<<(n + 31) / 32, 256, 0, stream>>>(bufDh, offs, csr, dinv, b2, bufEh, n);

    // gemm3: bufCh = fp16((bufEh@W3)*dinv) s32h  [K=52 (rows 50..51 zero), KR=50]
    gemm_tiled_h<52, 25, 144, 64, 32, true, false, 50><<<(n + 143) / 144, 256, 0, stream>>>(
        bufEh, W3, dinv, nullptr, bufCh, n);

    // agg3 + MLP head -> d_out
    agg3_mlp_h<<<(n + 63) / 64, 256, 0, stream>>>(
        bufCh, offs, csr, dinv, b3, Wl1, bl1, Wl2, bl2, Wl3, bl3, (float*)d_out, n);
}

// Round 2
// 253.307 us; speedup vs baseline: 1.1251x; 1.1251x over previous
//
#include <hip/hip_runtime.h>
#include <hip/hip_fp16.h>
#include <cstdint>

constexpr int BSHIFT = 9;               // 512 nodes per bucket
constexpr int NBUCK  = 256;             // max buckets (covers 131072 nodes)
constexpr int BUCKET_CAP = 6144;        // slot capacity; E/bucket ~ Poisson(5102), 14 sigma

struct alignas(16) H8 { __half2 a, b, c, d; };
struct alignas(8)  H4 { __half2 a, b; };

typedef _Float16 f16x8 __attribute__((ext_vector_type(8)));
typedef float    f32x4 __attribute__((ext_vector_type(4)));

__device__ __forceinline__ float4 add4(float4 a, float4 b) {
    return make_float4(a.x + b.x, a.y + b.y, a.z + b.z, a.w + b.w);
}
__device__ __forceinline__ float4 mul4s(float4 a, float s) {
    return make_float4(a.x * s, a.y * s, a.z * s, a.w * s);
}
__device__ __forceinline__ void acc_h8(float4& A0, float4& A1, const H8 v, float s) {
    float2 f0 = __half22float2(v.a), f1 = __half22float2(v.b);
    float2 f2 = __half22float2(v.c), f3 = __half22float2(v.d);
    A0.x = fmaf(f0.x, s, A0.x); A0.y = fmaf(f0.y, s, A0.y);
    A0.z = fmaf(f1.x, s, A0.z); A0.w = fmaf(f1.y, s, A0.w);
    A1.x = fmaf(f2.x, s, A1.x); A1.y = fmaf(f2.y, s, A1.y);
    A1.z = fmaf(f3.x, s, A1.z); A1.w = fmaf(f3.y, s, A1.w);
}

// ---------------- CSR build (R12-proven: LDS-local bucket_csr) ----------------

constexpr int EPT = 16;  // edges per thread; chunk = 4096
__global__ __launch_bounds__(256) void partition_edges(
    const int* __restrict__ src, const int* __restrict__ dst,
    int* __restrict__ bucketCur, int* __restrict__ pairs, int ne) {
    __shared__ int lcnt[NBUCK];
    __shared__ int lbase[NBUCK];
    int base = blockIdx.x * (256 * EPT);
    if (threadIdx.x < NBUCK) lcnt[threadIdx.x] = 0;
    __syncthreads();
    int2 ed[EPT];
    int  rnk[EPT];
#pragma unroll
    for (int j = 0; j < EPT; ++j) {
        int e = base + j * 256 + threadIdx.x;
        if (e < ne) {
            int d = dst[e];
            ed[j] = make_int2(src[e], d);
            rnk[j] = atomicAdd(&lcnt[d >> BSHIFT], 1);
        } else {
            ed[j].y = -1;
        }
    }
    __syncthreads();
    if (threadIdx.x < NBUCK) {
        int c = lcnt[threadIdx.x];
        lbase[threadIdx.x] = c ? atomicAdd(&bucketCur[threadIdx.x], c) : 0;
    }
    __syncthreads();
#pragma unroll
    for (int j = 0; j < EPT; ++j) {
        if (ed[j].y >= 0) {
            int b = ed[j].y >> BSHIFT;
            int p = lbase[b] + rnk[j];
            if (p < BUCKET_CAP)
                pairs[(size_t)b * BUCKET_CAP + p] =
                    (ed[j].x << BSHIFT) | (ed[j].y & ((1 << BSHIFT) - 1));
        }
    }
}

__global__ void scan_buckets(const int* __restrict__ bucketCnt, int* __restrict__ bucketBase,
                             int* __restrict__ offs, int n, int ne, int nbuckets) {
    __shared__ int tmp[256];
    int c = (threadIdx.x < (unsigned)nbuckets) ? bucketCnt[threadIdx.x] : 0;
    tmp[threadIdx.x] = c;
    __syncthreads();
    for (int off = 1; off < 256; off <<= 1) {
        int t = (threadIdx.x >= (unsigned)off) ? tmp[threadIdx.x - off] : 0;
        __syncthreads();
        tmp[threadIdx.x] += t;
        __syncthreads();
    }
    if (threadIdx.x < (unsigned)nbuckets) bucketBase[threadIdx.x] = tmp[threadIdx.x] - c;
    if (threadIdx.x == 0) offs[n] = ne;
}

__global__ __launch_bounds__(256) void bucket_csr(
    const int* __restrict__ pairs, const int* __restrict__ bucketCnt,
    const int* __restrict__ bucketBase, int* __restrict__ offs,
    float* __restrict__ dinv, int* __restrict__ csr, int n) {
    constexpr int BN = 1 << BSHIFT;  // 512
    __shared__ int hist[BN];
    __shared__ int cur[BN];
    __shared__ int tmp[256];
    int b = blockIdx.x;
    int cnt  = bucketCnt[b];
    int base = bucketBase[b];
    const int* pb = pairs + (size_t)b * BUCKET_CAP;
    int nodeLo = b << BSHIFT;

    hist[threadIdx.x] = 0;
    hist[threadIdx.x + 256] = 0;
    __syncthreads();
    for (int e = threadIdx.x; e < cnt; e += 256)
        atomicAdd(&hist[pb[e] & (BN - 1)], 1);
    __syncthreads();

    int l0 = 2 * threadIdx.x, l1 = l0 + 1;
    int h0 = hist[l0], h1 = hist[l1];
    tmp[threadIdx.x] = h0 + h1;
    __syncthreads();
    for (int off = 1; off < 256; off <<= 1) {
        int t = (threadIdx.x >= (unsigned)off) ? tmp[threadIdx.x - off] : 0;
        __syncthreads();
        tmp[threadIdx.x] += t;
        __syncthreads();
    }
    int e0 = tmp[threadIdx.x] - (h0 + h1);
    int e1 = e0 + h0;
    int g0 = nodeLo + l0, g1 = nodeLo + l1;
    if (g0 < n) { offs[g0] = base + e0; dinv[g0] = rsqrtf((float)(h0 + 1)); }
    if (g1 < n) { offs[g1] = base + e1; dinv[g1] = rsqrtf((float)(h1 + 1)); }
    cur[l0] = e0;
    cur[l1] = e1;
    __syncthreads();

    for (int e = threadIdx.x; e < cnt; e += 256) {
        int p = pb[e];
        int pos = atomicAdd(&cur[p & (BN - 1)], 1);
        csr[base + pos] = ((unsigned)p) >> BSHIFT;
    }
}

// ---------------- weight pack: fragment-ordered fp16 B-operands ----------------
// Fragment layout (mfma_f32_16x16x32_f16, B operand): lane l holds
// B[k = kf*32 + (l>>4)*8 + j][m = mt*16 + (l&15)], j=0..7 contiguous.
// P[frag][lane][8] halves; frag index = mt*KF + kf.
__global__ void pack_weights(const float* __restrict__ W1, const float* __restrict__ W2,
                             const float* __restrict__ W3,
                             __half* __restrict__ P1, __half* __restrict__ P2,
                             __half* __restrict__ P3) {
    int t = threadIdx.x;
    // P1: W1 [64 x 100] -> 7 mtiles x 2 kfrags
    for (int i = t; i < 7 * 2 * 64 * 8; i += 256) {
        int j = i & 7, lane = (i >> 3) & 63, f = i >> 9;
        int mt = f >> 1, kf = f & 1;
        int k = kf * 32 + (lane >> 4) * 8 + j;
        int m = mt * 16 + (lane & 15);
        P1[i] = __float2half_rn(m < 100 ? W1[k * 100 + m] : 0.0f);
    }
    // P2: W2 [100 x 50] -> pad [128 x 64]: 4 mtiles x 4 kfrags
    for (int i = t; i < 4 * 4 * 64 * 8; i += 256) {
        int j = i & 7, lane = (i >> 3) & 63, f = i >> 9;
        int mt = f >> 2, kf = f & 3;
        int k = kf * 32 + (lane >> 4) * 8 + j;
        int m = mt * 16 + (lane & 15);
        P2[i] = __float2half_rn((k < 100 && m < 50) ? W2[k * 50 + m] : 0.0f);
    }
    // P3: W3 [50 x 25] -> pad [64 x 32]: 2 mtiles x 2 kfrags
    for (int i = t; i < 2 * 2 * 64 * 8; i += 256) {
        int j = i & 7, lane = (i >> 3) & 63, f = i >> 9;
        int mt = f >> 1, kf = f & 1;
        int k = kf * 32 + (lane >> 4) * 8 + j;
        int m = mt * 16 + (lane & 15);
        P3[i] = __float2half_rn((k < 50 && m < 25) ? W3[k * 25 + m] : 0.0f);
    }
}

// ---------------- fp32 -> fp16 streaming convert, prescaled by dinv ----------------
__global__ void cvt_scale_f32_f16(const float* __restrict__ x, const float* __restrict__ dinv,
                                  __half* __restrict__ o, int n4) {
    int i = blockIdx.x * blockDim.x + threadIdx.x;
    if (i < n4) {
        float dv = dinv[i >> 4];          // 16 float4 per 64-wide row
        float4 v = ((const float4*)x)[i];
        H4 h;
        h.a = __floats2half2_rn(v.x * dv, v.y * dv);
        h.b = __floats2half2_rn(v.z * dv, v.w * dv);
        ((H4*)o)[i] = h;
    }
}

// ---------------- agg1: fp16 gather (K=64), rows pre-scaled by dinv[src] ----------------
__global__ __launch_bounds__(256) void agg1_h(
    const __half* __restrict__ s, const int* __restrict__ offs,
    const int* __restrict__ csr, const float* __restrict__ dinv,
    __half* __restrict__ out, int n) {
    int lane = threadIdx.x & 7;
    int node = blockIdx.x * 32 + (threadIdx.x >> 3);
    if (node >= n) return;
    int f0 = lane * 8;
    float dv = dinv[node];

    float4 z = make_float4(0.f, 0.f, 0.f, 0.f);
    float4 a00 = z, a01 = z, a10 = z, a11 = z, a20 = z, a21 = z, a30 = z, a31 = z;
    {
        H8 sv = *(const H8*)&s[(size_t)node * 64 + f0];   // y[node] = dinv*x -> self term
        acc_h8(a00, a01, sv, 1.0f);
    }
    int e0 = offs[node], e1 = offs[node + 1];
    int e = e0;
    for (; e + 4 <= e1; e += 4) {
        int i0 = csr[e], i1 = csr[e + 1], i2 = csr[e + 2], i3 = csr[e + 3];
        H8 v0 = *(const H8*)&s[(size_t)i0 * 64 + f0];
        H8 v1 = *(const H8*)&s[(size_t)i1 * 64 + f0];
        H8 v2 = *(const H8*)&s[(size_t)i2 * 64 + f0];
        H8 v3 = *(const H8*)&s[(size_t)i3 * 64 + f0];
        acc_h8(a00, a01, v0, 1.0f);
        acc_h8(a10, a11, v1, 1.0f);
        acc_h8(a20, a21, v2, 1.0f);
        acc_h8(a30, a31, v3, 1.0f);
    }
    for (; e < e1; ++e) {
        int sid = csr[e];
        H8 v = *(const H8*)&s[(size_t)sid * 64 + f0];
        acc_h8(a00, a01, v, 1.0f);
    }
    float4 A0 = add4(add4(a00, a10), add4(a20, a30));
    float4 A1 = add4(add4(a01, a11), add4(a21, a31));
    A0 = mul4s(A0, dv);
    A1 = mul4s(A1, dv);

    H8 h;
    h.a = __floats2half2_rn(A0.x, A0.y);
    h.b = __floats2half2_rn(A0.z, A0.w);
    h.c = __floats2half2_rn(A1.x, A1.y);
    h.d = __floats2half2_rn(A1.z, A1.w);
    *(H8*)&out[(size_t)node * 64 + f0] = h;
}

// ---------------- agg2: fp16 gather (M=50 in s64h rows), fp16 out (zero-padded) ---------
__global__ __launch_bounds__(256) void agg2_h16(
    const __half* __restrict__ s, const int* __restrict__ offs,
    const int* __restrict__ csr, const float* __restrict__ dinv,
    const float* __restrict__ b, __half* __restrict__ out, int n) {
    constexpr int MH = 50, SH = 64;
    int lane = threadIdx.x & 7;
    int node = blockIdx.x * 32 + (threadIdx.x >> 3);
    if (node >= n) return;
    int f0 = lane * 8;
    H8 zh{};
    if (f0 >= 56) {              // lane 7: pure zero-pad (halves 56..63)
        *(H8*)&out[(size_t)node * SH + f0] = zh;
        return;
    }
    float dv = dinv[node];

    float4 z = make_float4(0.f, 0.f, 0.f, 0.f);
    float4 a00 = z, a01 = z, a10 = z, a11 = z, a20 = z, a21 = z, a30 = z, a31 = z;
    {
        H8 sv = *(const H8*)&s[(size_t)node * SH + f0];
        acc_h8(a00, a01, sv, 1.0f);
    }
    int e0 = offs[node], e1 = offs[node + 1];
    int e = e0;
    for (; e + 4 <= e1; e += 4) {
        int i0 = csr[e], i1 = csr[e + 1], i2 = csr[e + 2], i3 = csr[e + 3];
        H8 v0 = *(const H8*)&s[(size_t)i0 * SH + f0];
        H8 v1 = *(const H8*)&s[(size_t)i1 * SH + f0];
        H8 v2 = *(const H8*)&s[(size_t)i2 * SH + f0];
        H8 v3 = *(const H8*)&s[(size_t)i3 * SH + f0];
        acc_h8(a00, a01, v0, 1.0f);
        acc_h8(a10, a11, v1, 1.0f);
        acc_h8(a20, a21, v2, 1.0f);
        acc_h8(a30, a31, v3, 1.0f);
    }
    for (; e < e1; ++e) {
        H8 v = *(const H8*)&s[(size_t)csr[e] * SH + f0];
        acc_h8(a00, a01, v, 1.0f);
    }
    float4 A0 = add4(add4(a00, a10), add4(a20, a30));
    float4 A1 = add4(add4(a01, a11), add4(a21, a31));
    float v[8] = {A0.x, A0.y, A0.z, A0.w, A1.x, A1.y, A1.z, A1.w};
#pragma unroll
    for (int i = 0; i < 8; ++i)
        v[i] = (f0 + i < MH) ? fmaxf(dv * v[i] + b[f0 + i], 0.0f) : 0.0f;
    H8 h;
    h.a = __floats2half2_rn(v[0], v[1]);
    h.b = __floats2half2_rn(v[2], v[3]);
    h.c = __floats2half2_rn(v[4], v[5]);
    h.d = __floats2half2_rn(v[6], v[7]);
    *(H8*)&out[(size_t)node * SH + f0] = h;
}

// ---------------- MFMA fused gemm1+gemm2 ----------------
// out = fp16( dinv * ( relu(x@W1 + b1) @ W2 ) ), x: [n x 64] fp16 node-major.
// A-frag: lane l holds A[l&15][(l>>4)*8+j] -> one 16B load per kfrag.
// D-frag: row=(l>>4)*4+i, col=l&15.
// H (100-wide relu intermediate) transposes through LDS (pad 136 halves -> 2-way banks).
constexpr int HP = 136;
__global__ __launch_bounds__(256, 4) void gemm12_mfma(
    const __half* __restrict__ x, const __half* __restrict__ P1,
    const float* __restrict__ b1, const __half* __restrict__ P2,
    const float* __restrict__ dinv, __half* __restrict__ out, int n) {
    __shared__ _Float16 Hs[128 * HP];   // 34.8 KB
    int tid = threadIdx.x;
    int lane = tid & 63;
    int w = tid >> 6;
    int lg = lane >> 4;        // k-group
    int lr = lane & 15;        // A-row / D-col
    int blockBase = blockIdx.x * 128;
    int waveBase  = blockBase + w * 32;

    // zero H pad cols 112..127 (W2 kfrag 3 reads them; keep finite)
    for (int i = tid; i < 128 * 2; i += 256) {
        f16x8 zz = {};
        *(f16x8*)&Hs[(i >> 1) * HP + 112 + (i & 1) * 8] = zz;
    }

    float b1v[7];
#pragma unroll
    for (int mt = 0; mt < 7; ++mt) {
        int m = mt * 16 + lr;
        b1v[mt] = (m < 100) ? b1[m] : 0.0f;
    }

    // ---- phase 1: H = relu(x@W1 + b1) -> LDS ----
    const f16x8* P1v = (const f16x8*)P1;
#pragma unroll
    for (int rt = 0; rt < 2; ++rt) {
        int rowG = waveBase + rt * 16 + lr;
        f16x8 a0 = {}, a1 = {};
        if (rowG < n) {
            a0 = *(const f16x8*)&x[(size_t)rowG * 64 + lg * 8];
            a1 = *(const f16x8*)&x[(size_t)rowG * 64 + 32 + lg * 8];
        }
        int hbase = w * 32 + rt * 16;
#pragma unroll
        for (int mt = 0; mt < 7; ++mt) {
            f16x8 w0 = P1v[(mt * 2 + 0) * 64 + lane];
            f16x8 w1 = P1v[(mt * 2 + 1) * 64 + lane];
            f32x4 acc = {};
            acc = __builtin_amdgcn_mfma_f32_16x16x32_f16(a0, w0, acc, 0, 0, 0);
            acc = __builtin_amdgcn_mfma_f32_16x16x32_f16(a1, w1, acc, 0, 0, 0);
            int col = mt * 16 + lr;
#pragma unroll
            for (int i = 0; i < 4; ++i) {
                int rloc = hbase + lg * 4 + i;
                Hs[rloc * HP + col] = (_Float16)fmaxf(acc[i] + b1v[mt], 0.0f);
            }
        }
    }
    __syncthreads();

    // ---- phase 2: out = (H@W2) * dinv ----
    const f16x8* P2v = (const f16x8*)P2;
#pragma unroll
    for (int mt = 0; mt < 4; ++mt) {
        f16x8 w0 = P2v[(mt * 4 + 0) * 64 + lane];
        f16x8 w1 = P2v[(mt * 4 + 1) * 64 + lane];
        f16x8 w2 = P2v[(mt * 4 + 2) * 64 + lane];
        f16x8 w3 = P2v[(mt * 4 + 3) * 64 + lane];
#pragma unroll
        for (int rt = 0; rt < 2; ++rt) {
            int lbase = w * 32 + rt * 16;
            const _Float16* hrow = &Hs[(size_t)(lbase + lr) * HP];
            f16x8 a0 = *(const f16x8*)&hrow[lg * 8];
            f16x8 a1 = *(const f16x8*)&hrow[32 + lg * 8];
            f16x8 a2 = *(const f16x8*)&hrow[64 + lg * 8];
            f16x8 a3 = *(const f16x8*)&hrow[96 + lg * 8];
            f32x4 acc = {};
            acc = __builtin_amdgcn_mfma_f32_16x16x32_f16(a0, w0, acc, 0, 0, 0);
            acc = __builtin_amdgcn_mfma_f32_16x16x32_f16(a1, w1, acc, 0, 0, 0);
            acc = __builtin_amdgcn_mfma_f32_16x16x32_f16(a2, w2, acc, 0, 0, 0);
            acc = __builtin_amdgcn_mfma_f32_16x16x32_f16(a3, w3, acc, 0, 0, 0);
            int col = mt * 16 + lr;
#pragma unroll
            for (int i = 0; i < 4; ++i) {
                int node = blockBase + lbase + lg * 4 + i;
                if (node < n)
                    out[(size_t)node * 64 + col] = __float2half_rn(acc[i] * dinv[node]);
            }
        }
    }
}

// ---------------- MFMA gemm3: out = fp16( dinv * (x@W3) ), [n x 64] -> [n x 32] -------
__global__ __launch_bounds__(256, 4) void gemm3_mfma(
    const __half* __restrict__ x, const __half* __restrict__ P3,
    const float* __restrict__ dinv, __half* __restrict__ out, int n) {
    int tid = threadIdx.x, lane = tid & 63, w = tid >> 6;
    int lg = lane >> 4, lr = lane & 15;
    int waveBase = blockIdx.x * 128 + w * 32;
    const f16x8* P3v = (const f16x8*)P3;
    f16x8 w00 = P3v[0 * 64 + lane], w01 = P3v[1 * 64 + lane];
    f16x8 w10 = P3v[2 * 64 + lane], w11 = P3v[3 * 64 + lane];
#pragma unroll
    for (int rt = 0; rt < 2; ++rt) {
        int rowG = waveBase + rt * 16 + lr;
        f16x8 a0 = {}, a1 = {};
        if (rowG < n) {
            a0 = *(const f16x8*)&x[(size_t)rowG * 64 + lg * 8];
            a1 = *(const f16x8*)&x[(size_t)rowG * 64 + 32 + lg * 8];
        }
#pragma unroll
        for (int mt = 0; mt < 2; ++mt) {
            f32x4 acc = {};
            acc = __builtin_amdgcn_mfma_f32_16x16x32_f16(a0, mt ? w10 : w00, acc, 0, 0, 0);
            acc = __builtin_amdgcn_mfma_f32_16x16x32_f16(a1, mt ? w11 : w01, acc, 0, 0, 0);
            int col = mt * 16 + lr;
#pragma unroll
            for (int i = 0; i < 4; ++i) {
                int node = waveBase + rt * 16 + lg * 4 + i;
                if (node < n)
                    out[(size_t)node * 32 + col] = __float2half_rn(acc[i] * dinv[node]);
            }
        }
    }
}

// ---------------- agg3 (fp16 gather, 1 line/row) + MLP head ----------------
__global__ __launch_bounds__(256) void agg3_mlp_h(
    const __half* __restrict__ s, const int* __restrict__ offs,
    const int* __restrict__ csr, const float* __restrict__ dinv,
    const float* __restrict__ bg,
    const float* __restrict__ Wl1, const float* __restrict__ bl1,
    const float* __restrict__ Wl2, const float* __restrict__ bl2,
    const float* __restrict__ Wl3, const float* __restrict__ bl3,
    float* __restrict__ out, int n) {
    constexpr int MH = 25, SH = 32, LPN = 4;
    __shared__ float W1s[625], W2s[250], W3s[10], b1s[25], b2s[10];
    __shared__ float accs[64 * 26];
    __shared__ float b3s;

    for (int i = threadIdx.x; i < 625; i += 256) W1s[i] = Wl1[i];
    for (int i = threadIdx.x; i < 250; i += 256) W2s[i] = Wl2[i];
    if (threadIdx.x < 10) { W3s[threadIdx.x] = Wl3[threadIdx.x]; b2s[threadIdx.x] = bl2[threadIdx.x]; }
    if (threadIdx.x < 25) b1s[threadIdx.x] = bl1[threadIdx.x];
    if (threadIdx.x == 0) b3s = bl3[0];

    int lane = threadIdx.x % LPN;
    int nl   = threadIdx.x / LPN;
    int node = blockIdx.x * 64 + nl;
    int f0 = lane * 8;

    if (node < n && f0 < MH) {
        float dv = dinv[node];
        float4 z = make_float4(0.f, 0.f, 0.f, 0.f);
        float4 a00 = z, a01 = z, a10 = z, a11 = z, a20 = z, a21 = z, a30 = z, a31 = z;
        {
            H8 sv = *(const H8*)&s[(size_t)node * SH + f0];
            acc_h8(a00, a01, sv, 1.0f);
        }
        int e0 = offs[node], e1 = offs[node + 1];
        int e = e0;
        for (; e + 4 <= e1; e += 4) {
            int i0 = csr[e], i1 = csr[e + 1], i2 = csr[e + 2], i3 = csr[e + 3];
            H8 v0 = *(const H8*)&s[(size_t)i0 * SH + f0];
            H8 v1 = *(const H8*)&s[(size_t)i1 * SH + f0];
            H8 v2 = *(const H8*)&s[(size_t)i2 * SH + f0];
            H8 v3 = *(const H8*)&s[(size_t)i3 * SH + f0];
            acc_h8(a00, a01, v0, 1.0f);
            acc_h8(a10, a11, v1, 1.0f);
            acc_h8(a20, a21, v2, 1.0f);
            acc_h8(a30, a31, v3, 1.0f);
        }
        for (; e < e1; ++e) {
            H8 v = *(const H8*)&s[(size_t)csr[e] * SH + f0];
            acc_h8(a00, a01, v, 1.0f);
        }
        float4 A0 = add4(add4(a00, a10), add4(a20, a30));
        float4 A1 = add4(add4(a01, a11), add4(a21, a31));
        float v[8] = {A0.x, A0.y, A0.z, A0.w, A1.x, A1.y, A1.z, A1.w};
#pragma unroll
        for (int i = 0; i < 8; ++i)
            if (f0 + i < MH)
                accs[nl * 26 + f0 + i] = fmaxf(dv * v[i] + bg[f0 + i], 0.0f);
    }
    __syncthreads();

    if (threadIdx.x < 64) {
        int nd = blockIdx.x * 64 + threadIdx.x;
        if (nd < n) {
            const float* xr = &accs[threadIdx.x * 26];
            float h1[25];
#pragma unroll
            for (int m = 0; m < 25; ++m) {
                float a = b1s[m];
#pragma unroll
                for (int k = 0; k < 25; ++k) a = fmaf(xr[k], W1s[k * 25 + m], a);
                h1[m] = fmaxf(a, 0.0f);
            }
            float h2[10];
#pragma unroll
            for (int m = 0; m < 10; ++m) {
                float a = b2s[m];
#pragma unroll
                for (int k = 0; k < 25; ++k) a = fmaf(h1[k], W2s[k * 10 + m], a);
                h2[m] = fmaxf(a, 0.0f);
            }
            float a = b3s;
#pragma unroll
            for (int k = 0; k < 10; ++k) a = fmaf(h2[k], W3s[k], a);
            out[nd] = fmaxf(a, 0.0f);
        }
    }
}

// ---------------- launch ----------------

extern "C" void kernel_launch(void* const* d_in, const int* in_sizes, int n_in,
                              void* d_out, int out_size, void* d_ws, size_t ws_size,
                              hipStream_t stream) {
    const float* x0  = (const float*)d_in[0];
    const float* W1  = (const float*)d_in[1];
    const float* b1  = (const float*)d_in[2];
    const float* W2  = (const float*)d_in[3];
    const float* b2  = (const float*)d_in[4];
    const float* W3  = (const float*)d_in[5];
    const float* b3  = (const float*)d_in[6];
    const float* Wl1 = (const float*)d_in[7];
    const float* bl1 = (const float*)d_in[8];
    const float* Wl2 = (const float*)d_in[9];
    const float* bl2 = (const float*)d_in[10];
    const float* Wl3 = (const float*)d_in[11];
    const float* bl3 = (const float*)d_in[12];
    const int*   edge = (const int*)d_in[13];

    int n  = in_sizes[0] / 64;      // 100000
    int ne = in_sizes[13] / 2;      // 1000000
    const int* esrc = edge;
    const int* edst = edge + ne;

    char* ws = (char*)d_ws;
    auto alloc = [&](size_t bytes) {
        char* p = ws;
        ws += (bytes + 255) & ~(size_t)255;
        return p;
    };
    int*    offs       = (int*)alloc((size_t)(n + 1) * 4);
    int*    bucketCur  = (int*)alloc(NBUCK * 4);
    int*    bucketBase = (int*)alloc(NBUCK * 4);
    int*    csr        = (int*)alloc((size_t)ne * 4);
    float*  dinv       = (float*)alloc((size_t)n * 4);
    __half* x0h        = (__half*)alloc((size_t)n * 64 * 2);   // fp16 s64h (cvt out, dinv-prescaled)
    __half* bufAh      = (__half*)alloc((size_t)n * 64 * 2);   // fp16 s64h (agg1 out)
    __half* bufDh      = (__half*)alloc((size_t)n * 64 * 2);   // fp16 s64h (gemm12 out)
    __half* P1         = (__half*)alloc(7 * 2 * 64 * 8 * 2);   // packed W1 frags
    __half* P2         = (__half*)alloc(4 * 4 * 64 * 8 * 2);   // packed W2 frags
    __half* P3         = (__half*)alloc(2 * 2 * 64 * 8 * 2);   // packed W3 frags
    // aliases (ordered lifetimes):
    //   pairs (6.3MB) in bufDh: consumed by bucket_csr before gemm12 writes bufDh
    //   bufEh (agg2 out, s64h) aliases x0h (dead after agg1)
    //   bufCh (gemm3 out, s32h) aliases bufAh (dead after gemm12 phase1)
    int*    pairs = (int*)bufDh;
    __half* bufEh = x0h;
    __half* bufCh = bufAh;
    (void)ws_size; (void)n_in; (void)out_size;

    int nbuckets = (n + (1 << BSHIFT) - 1) >> BSHIFT;   // 196

    // weight fragment pack (tiny, one block)
    pack_weights<<<1, 256, 0, stream>>>(W1, W2, W3, P1, P2, P3);

    // CSR + dinv (memset + 3 dispatches; R12-proven LDS-local scatter)
    hipMemsetAsync(bucketCur, 0, NBUCK * 4, stream);
    partition_edges<<<(ne + 256 * EPT - 1) / (256 * EPT), 256, 0, stream>>>(
        esrc, edst, bucketCur, pairs, ne);
    scan_buckets<<<1, 256, 0, stream>>>(bucketCur, bucketBase, offs, n, ne, nbuckets);
    bucket_csr<<<nbuckets, 256, 0, stream>>>(pairs, bucketCur, bucketBase, offs, dinv, csr, n);

    // x0h = fp16(dinv * x0)  (prescale: agg1 no longer gathers dinv per edge)
    cvt_scale_f32_f16<<<(n * 16 + 255) / 256, 256, 0, stream>>>(x0, dinv, x0h, n * 16);

    // agg1: bufAh = fp16(ÂX)
    agg1_h<<<(n + 31) / 32, 256, 0, stream>>>(x0h, offs, csr, dinv, bufAh, n);

    // gemm12 (MFMA): bufDh = fp16(dinv * (relu(bufAh@W1+b1) @ W2))
    gemm12_mfma<<<(n + 127) / 128, 256, 0, stream>>>(bufAh, P1, b1, P2, dinv, bufDh, n);

    // agg2: bufEh = fp16(relu(dinv*agg(bufDh)+b2)), zero-padded to 64h rows
    agg2_h16<<<(n + 31) / 32, 256, 0, stream>>>(bufDh, offs, csr, dinv, b2, bufEh, n);

    // gemm3 (MFMA): bufCh = fp16((bufEh@W3)*dinv) s32h
    gemm3_mfma<<<(n + 127) / 128, 256, 0, stream>>>(bufEh, P3, dinv, bufCh, n);

    // agg3 + MLP head -> d_out
    agg3_mlp_h<<<(n + 63) / 64, 256, 0, stream>>>(
        bufCh, offs, csr, dinv, b3, Wl1, bl1, Wl2, bl2, Wl3, bl3, (float*)d_out, n);
}

// Round 3
// 230.784 us; speedup vs baseline: 1.2350x; 1.0976x over previous
//
#include <hip/hip_runtime.h>
#include <hip/hip_fp16.h>
#include <cstdint>

constexpr int BSHIFT = 9;               // 512 nodes per bucket
constexpr int NBUCK  = 256;             // max buckets (covers 131072 nodes)
constexpr int BUCKET_CAP = 6144;        // slot capacity; E/bucket ~ Poisson(5102), 14 sigma

struct alignas(16) H8 { __half2 a, b, c, d; };
struct alignas(8)  H4 { __half2 a, b; };

typedef _Float16 f16x8 __attribute__((ext_vector_type(8)));
typedef float    f32x4 __attribute__((ext_vector_type(4)));

__device__ __forceinline__ float4 add4(float4 a, float4 b) {
    return make_float4(a.x + b.x, a.y + b.y, a.z + b.z, a.w + b.w);
}
__device__ __forceinline__ float4 mul4s(float4 a, float s) {
    return make_float4(a.x * s, a.y * s, a.z * s, a.w * s);
}
__device__ __forceinline__ void acc_h8(float4& A0, float4& A1, const H8 v, float s) {
    float2 f0 = __half22float2(v.a), f1 = __half22float2(v.b);
    float2 f2 = __half22float2(v.c), f3 = __half22float2(v.d);
    A0.x = fmaf(f0.x, s, A0.x); A0.y = fmaf(f0.y, s, A0.y);
    A0.z = fmaf(f1.x, s, A0.z); A0.w = fmaf(f1.y, s, A0.w);
    A1.x = fmaf(f2.x, s, A1.x); A1.y = fmaf(f2.y, s, A1.y);
    A1.z = fmaf(f3.x, s, A1.z); A1.w = fmaf(f3.y, s, A1.w);
}

// ---------------- partition_edges + weight-frag pack (merged) ----------------
// Fragment layout (mfma_f32_16x16x32_f16, B operand): lane l holds
// B[k = kf*32 + (l>>4)*8 + j][m = mt*16 + (l&15)], j=0..7 contiguous.
// P[frag][lane][8] halves; frag index = mt*KF + kf.

constexpr int EPT = 16;  // edges per thread; chunk = 4096
__global__ __launch_bounds__(256) void partition_pack(
    const int* __restrict__ src, const int* __restrict__ dst,
    int* __restrict__ bucketCur, int* __restrict__ pairs, int ne, int nEdgeBlocks,
    const float* __restrict__ W1, const float* __restrict__ W2,
    const float* __restrict__ W3,
    __half* __restrict__ P1, __half* __restrict__ P2, __half* __restrict__ P3) {
    if (blockIdx.x == (unsigned)nEdgeBlocks) {
        // ---- pack block ----
        int t = threadIdx.x;
        for (int i = t; i < 7 * 2 * 64 * 8; i += 256) {      // W1 [64x100] -> 7mt x 2kf
            int j = i & 7, lane = (i >> 3) & 63, f = i >> 9;
            int mt = f >> 1, kf = f & 1;
            int k = kf * 32 + (lane >> 4) * 8 + j;
            int m = mt * 16 + (lane & 15);
            P1[i] = __float2half_rn(m < 100 ? W1[k * 100 + m] : 0.0f);
        }
        for (int i = t; i < 4 * 4 * 64 * 8; i += 256) {      // W2 [100x50] -> [128x64]
            int j = i & 7, lane = (i >> 3) & 63, f = i >> 9;
            int mt = f >> 2, kf = f & 3;
            int k = kf * 32 + (lane >> 4) * 8 + j;
            int m = mt * 16 + (lane & 15);
            P2[i] = __float2half_rn((k < 100 && m < 50) ? W2[k * 50 + m] : 0.0f);
        }
        for (int i = t; i < 2 * 2 * 64 * 8; i += 256) {      // W3 [50x25] -> [64x32]
            int j = i & 7, lane = (i >> 3) & 63, f = i >> 9;
            int mt = f >> 1, kf = f & 1;
            int k = kf * 32 + (lane >> 4) * 8 + j;
            int m = mt * 16 + (lane & 15);
            P3[i] = __float2half_rn((k < 50 && m < 25) ? W3[k * 25 + m] : 0.0f);
        }
        return;
    }
    __shared__ int lcnt[NBUCK];
    __shared__ int lbase[NBUCK];
    int base = blockIdx.x * (256 * EPT);
    if (threadIdx.x < NBUCK) lcnt[threadIdx.x] = 0;
    __syncthreads();
    int2 ed[EPT];
    int  rnk[EPT];
#pragma unroll
    for (int j = 0; j < EPT; ++j) {
        int e = base + j * 256 + threadIdx.x;
        if (e < ne) {
            int d = dst[e];
            ed[j] = make_int2(src[e], d);
            rnk[j] = atomicAdd(&lcnt[d >> BSHIFT], 1);
        } else {
            ed[j].y = -1;
        }
    }
    __syncthreads();
    if (threadIdx.x < NBUCK) {
        int c = lcnt[threadIdx.x];
        lbase[threadIdx.x] = c ? atomicAdd(&bucketCur[threadIdx.x], c) : 0;
    }
    __syncthreads();
#pragma unroll
    for (int j = 0; j < EPT; ++j) {
        if (ed[j].y >= 0) {
            int b = ed[j].y >> BSHIFT;
            int p = lbase[b] + rnk[j];
            if (p < BUCKET_CAP)
                pairs[(size_t)b * BUCKET_CAP + p] =
                    (ed[j].x << BSHIFT) | (ed[j].y & ((1 << BSHIFT) - 1));
        }
    }
}

// ---------------- bucket_csr with internal bucket-base scan ----------------
__global__ __launch_bounds__(256) void bucket_csr_scan(
    const int* __restrict__ pairs, const int* __restrict__ bucketCnt,
    int* __restrict__ offs, float* __restrict__ dinv, int* __restrict__ csr,
    int n, int ne, int nbuckets) {
    constexpr int BN = 1 << BSHIFT;  // 512
    __shared__ int hist[BN];
    __shared__ int cur[BN];
    __shared__ int tmp[256];
    __shared__ int baseS;
    int b = blockIdx.x;
    int t = threadIdx.x;

    // bucket-base prefix over bucketCnt (replaces scan_buckets kernel)
    int c = (t < (unsigned)nbuckets) ? bucketCnt[t] : 0;
    tmp[t] = c;
    __syncthreads();
    for (int off = 1; off < 256; off <<= 1) {
        int v = (t >= (unsigned)off) ? tmp[t - off] : 0;
        __syncthreads();
        tmp[t] += v;
        __syncthreads();
    }
    if (t == 0) {
        baseS = b ? tmp[b - 1] : 0;
        if (b == 0) offs[n] = ne;
    }
    __syncthreads();
    int base = baseS;
    int cnt  = bucketCnt[b];
    const int* pb = pairs + (size_t)b * BUCKET_CAP;
    int nodeLo = b << BSHIFT;

    hist[t] = 0;
    hist[t + 256] = 0;
    __syncthreads();
    for (int e = t; e < cnt; e += 256)
        atomicAdd(&hist[pb[e] & (BN - 1)], 1);
    __syncthreads();

    int l0 = 2 * t, l1 = l0 + 1;
    int h0 = hist[l0], h1 = hist[l1];
    tmp[t] = h0 + h1;
    __syncthreads();
    for (int off = 1; off < 256; off <<= 1) {
        int v = (t >= (unsigned)off) ? tmp[t - off] : 0;
        __syncthreads();
        tmp[t] += v;
        __syncthreads();
    }
    int e0 = tmp[t] - (h0 + h1);
    int e1 = e0 + h0;
    int g0 = nodeLo + l0, g1 = nodeLo + l1;
    if (g0 < n) { offs[g0] = base + e0; dinv[g0] = rsqrtf((float)(h0 + 1)); }
    if (g1 < n) { offs[g1] = base + e1; dinv[g1] = rsqrtf((float)(h1 + 1)); }
    cur[l0] = e0;
    cur[l1] = e1;
    __syncthreads();

    for (int e = t; e < cnt; e += 256) {
        int p = pb[e];
        int pos = atomicAdd(&cur[p & (BN - 1)], 1);
        csr[base + pos] = ((unsigned)p) >> BSHIFT;
    }
}

// ---------------- fp32 -> fp16 streaming convert, prescaled by dinv ----------------
__global__ void cvt_scale_f32_f16(const float* __restrict__ x, const float* __restrict__ dinv,
                                  __half* __restrict__ o, int n4) {
    int i = blockIdx.x * blockDim.x + threadIdx.x;
    if (i < n4) {
        float dv = dinv[i >> 4];          // 16 float4 per 64-wide row
        float4 v = ((const float4*)x)[i];
        H4 h;
        h.a = __floats2half2_rn(v.x * dv, v.y * dv);
        h.b = __floats2half2_rn(v.z * dv, v.w * dv);
        ((H4*)o)[i] = h;
    }
}

// ---------------- fused agg1 + gemm1 + gemm2 (MFMA) ----------------
// Block = 64 nodes, 4 waves, wave w owns nodes [w*16, w*16+16).
// Phase 0: agg1 (gather x0h rows, dinv-prescaled) -> Xs (fp16, 16B-aligned rows).
// Phase 1: H = relu(Xs@W1 + b1) -> Hs.   Phase 2: out = (Hs@W2)*dinv.
constexpr int XSP = 72;   // Xs row stride, halves (144B = 16B-aligned, 4-bank shift/row)
constexpr int HPS = 136;  // Hs row stride, halves (272B = 16B-aligned)
__global__ __launch_bounds__(256, 4) void agg1gemm12(
    const __half* __restrict__ x, const int* __restrict__ offs,
    const int* __restrict__ csr, const float* __restrict__ dinv,
    const __half* __restrict__ P1, const float* __restrict__ b1,
    const __half* __restrict__ P2, __half* __restrict__ out, int n) {
    __shared__ alignas(16) _Float16 Xs[64 * XSP];   // 9.2 KB
    __shared__ alignas(16) _Float16 Hs[64 * HPS];   // 17.4 KB
    int tid = threadIdx.x, lane = tid & 63, w = tid >> 6;
    int lg = lane >> 4, lr = lane & 15;
    int blockBase = blockIdx.x * 64;

    // zero Hs pad cols 112..127 (read by W2 kfrag3; must be finite)
    for (int i = tid; i < 64 * 2; i += 256) {
        f16x8 zz = {};
        *(f16x8*)&Hs[(i >> 1) * HPS + 112 + (i & 1) * 8] = zz;
    }

    // ---- phase 0: aggregate 16 nodes/wave (2 passes of 8) ----
    int f0 = (lane & 7) * 8;
#pragma unroll
    for (int p = 0; p < 2; ++p) {
        int nl = w * 16 + p * 8 + (lane >> 3);
        int node = blockBase + nl;
        float4 z4 = make_float4(0.f, 0.f, 0.f, 0.f);
        float4 a00 = z4, a01 = z4, a10 = z4, a11 = z4, a20 = z4, a21 = z4, a30 = z4, a31 = z4;
        float dv = 0.0f;
        if (node < n) {
            dv = dinv[node];
            H8 sv = *(const H8*)&x[(size_t)node * 64 + f0];   // self term (prescaled)
            acc_h8(a00, a01, sv, 1.0f);
            int e0 = offs[node], e1 = offs[node + 1];
            int e = e0;
            for (; e + 4 <= e1; e += 4) {
                int i0 = csr[e], i1 = csr[e + 1], i2 = csr[e + 2], i3 = csr[e + 3];
                H8 v0 = *(const H8*)&x[(size_t)i0 * 64 + f0];
                H8 v1 = *(const H8*)&x[(size_t)i1 * 64 + f0];
                H8 v2 = *(const H8*)&x[(size_t)i2 * 64 + f0];
                H8 v3 = *(const H8*)&x[(size_t)i3 * 64 + f0];
                acc_h8(a00, a01, v0, 1.0f);
                acc_h8(a10, a11, v1, 1.0f);
                acc_h8(a20, a21, v2, 1.0f);
                acc_h8(a30, a31, v3, 1.0f);
            }
            for (; e < e1; ++e) {
                H8 v = *(const H8*)&x[(size_t)csr[e] * 64 + f0];
                acc_h8(a00, a01, v, 1.0f);
            }
        }
        float4 A0 = add4(add4(a00, a10), add4(a20, a30));
        float4 A1 = add4(add4(a01, a11), add4(a21, a31));
        A0 = mul4s(A0, dv);
        A1 = mul4s(A1, dv);
        H8 h;
        h.a = __floats2half2_rn(A0.x, A0.y);
        h.b = __floats2half2_rn(A0.z, A0.w);
        h.c = __floats2half2_rn(A1.x, A1.y);
        h.d = __floats2half2_rn(A1.z, A1.w);
        *(H8*)&Xs[nl * XSP + f0] = h;
    }
    __syncthreads();

    // ---- phase 1: H = relu(Xs@W1 + b1) ----
    const f16x8* P1v = (const f16x8*)P1;
    float b1v[7];
#pragma unroll
    for (int mt = 0; mt < 7; ++mt) {
        int m = mt * 16 + lr;
        b1v[mt] = (m < 100) ? b1[m] : 0.0f;
    }
    {
        int rowL = w * 16 + lr;
        f16x8 a0 = *(const f16x8*)&Xs[rowL * XSP + lg * 8];
        f16x8 a1 = *(const f16x8*)&Xs[rowL * XSP + 32 + lg * 8];
        int hbase = w * 16;
#pragma unroll
        for (int mt = 0; mt < 7; ++mt) {
            f16x8 w0 = P1v[(mt * 2 + 0) * 64 + lane];
            f16x8 w1 = P1v[(mt * 2 + 1) * 64 + lane];
            f32x4 acc = {};
            acc = __builtin_amdgcn_mfma_f32_16x16x32_f16(a0, w0, acc, 0, 0, 0);
            acc = __builtin_amdgcn_mfma_f32_16x16x32_f16(a1, w1, acc, 0, 0, 0);
            int col = mt * 16 + lr;
#pragma unroll
            for (int i = 0; i < 4; ++i) {
                int rloc = hbase + lg * 4 + i;
                Hs[rloc * HPS + col] = (_Float16)fmaxf(acc[i] + b1v[mt], 0.0f);
            }
        }
    }
    __syncthreads();

    // ---- phase 2: out = (Hs@W2) * dinv ----
    const f16x8* P2v = (const f16x8*)P2;
#pragma unroll
    for (int mt = 0; mt < 4; ++mt) {
        f16x8 w0 = P2v[(mt * 4 + 0) * 64 + lane];
        f16x8 w1 = P2v[(mt * 4 + 1) * 64 + lane];
        f16x8 w2 = P2v[(mt * 4 + 2) * 64 + lane];
        f16x8 w3 = P2v[(mt * 4 + 3) * 64 + lane];
        int lbase = w * 16;
        const _Float16* hrow = &Hs[(size_t)(lbase + lr) * HPS];
        f16x8 a0 = *(const f16x8*)&hrow[lg * 8];
        f16x8 a1 = *(const f16x8*)&hrow[32 + lg * 8];
        f16x8 a2 = *(const f16x8*)&hrow[64 + lg * 8];
        f16x8 a3 = *(const f16x8*)&hrow[96 + lg * 8];
        f32x4 acc = {};
        acc = __builtin_amdgcn_mfma_f32_16x16x32_f16(a0, w0, acc, 0, 0, 0);
        acc = __builtin_amdgcn_mfma_f32_16x16x32_f16(a1, w1, acc, 0, 0, 0);
        acc = __builtin_amdgcn_mfma_f32_16x16x32_f16(a2, w2, acc, 0, 0, 0);
        acc = __builtin_amdgcn_mfma_f32_16x16x32_f16(a3, w3, acc, 0, 0, 0);
        int col = mt * 16 + lr;
#pragma unroll
        for (int i = 0; i < 4; ++i) {
            int node = blockBase + lbase + lg * 4 + i;
            if (node < n)
                out[(size_t)node * 64 + col] = __float2half_rn(acc[i] * dinv[node]);
        }
    }
}

// ---------------- fused agg2 + gemm3 (MFMA) ----------------
// Block = 32 nodes. Phase A: agg2 -> Ys (fp16 relu'd 50-wide rows, zero-padded to 64).
// Phase B: out = (Ys@W3)*dinv, wave w handles (rt=w>>1, mt=w&1).
constexpr int YP = 72;
__global__ __launch_bounds__(256) void agg2g3(
    const __half* __restrict__ s, const int* __restrict__ offs,
    const int* __restrict__ csr, const float* __restrict__ dinv,
    const float* __restrict__ b2, const __half* __restrict__ P3,
    __half* __restrict__ out, int n) {
    constexpr int MH = 50, SH = 64;
    __shared__ alignas(16) _Float16 Ys[32 * YP];   // 4.6 KB
    int tid = threadIdx.x, lane = tid & 63, w = tid >> 6;
    int lg = lane >> 4, lr = lane & 15;
    int blockBase = blockIdx.x * 32;

    // ---- phase A: aggregate (8 lanes per node) ----
    int nodeL = tid >> 3;
    int f0 = (tid & 7) * 8;
    int node = blockBase + nodeL;
    float v[8] = {0.f, 0.f, 0.f, 0.f, 0.f, 0.f, 0.f, 0.f};
    if (node < n && f0 < 56) {
        float dv = dinv[node];
        float4 z4 = make_float4(0.f, 0.f, 0.f, 0.f);
        float4 a00 = z4, a01 = z4, a10 = z4, a11 = z4, a20 = z4, a21 = z4, a30 = z4, a31 = z4;
        {
            H8 sv = *(const H8*)&s[(size_t)node * SH + f0];
            acc_h8(a00, a01, sv, 1.0f);
        }
        int e0 = offs[node], e1 = offs[node + 1];
        int e = e0;
        for (; e + 4 <= e1; e += 4) {
            int i0 = csr[e], i1 = csr[e + 1], i2 = csr[e + 2], i3 = csr[e + 3];
            H8 v0 = *(const H8*)&s[(size_t)i0 * SH + f0];
            H8 v1 = *(const H8*)&s[(size_t)i1 * SH + f0];
            H8 v2 = *(const H8*)&s[(size_t)i2 * SH + f0];
            H8 v3 = *(const H8*)&s[(size_t)i3 * SH + f0];
            acc_h8(a00, a01, v0, 1.0f);
            acc_h8(a10, a11, v1, 1.0f);
            acc_h8(a20, a21, v2, 1.0f);
            acc_h8(a30, a31, v3, 1.0f);
        }
        for (; e < e1; ++e) {
            H8 vv = *(const H8*)&s[(size_t)csr[e] * SH + f0];
            acc_h8(a00, a01, vv, 1.0f);
        }
        float4 A0 = add4(add4(a00, a10), add4(a20, a30));
        float4 A1 = add4(add4(a01, a11), add4(a21, a31));
        float vr[8] = {A0.x, A0.y, A0.z, A0.w, A1.x, A1.y, A1.z, A1.w};
#pragma unroll
        for (int i = 0; i < 8; ++i)
            v[i] = (f0 + i < MH) ? fmaxf(dv * vr[i] + b2[f0 + i], 0.0f) : 0.0f;
    }
    {
        H8 h;
        h.a = __floats2half2_rn(v[0], v[1]);
        h.b = __floats2half2_rn(v[2], v[3]);
        h.c = __floats2half2_rn(v[4], v[5]);
        h.d = __floats2half2_rn(v[6], v[7]);
        *(H8*)&Ys[nodeL * YP + f0] = h;
    }
    __syncthreads();

    // ---- phase B: out = (Ys@W3) * dinv ----
    int rt = w >> 1, mt = w & 1;
    const f16x8* P3v = (const f16x8*)P3;
    f16x8 w0 = P3v[(mt * 2 + 0) * 64 + lane];
    f16x8 w1 = P3v[(mt * 2 + 1) * 64 + lane];
    int rowL = rt * 16 + lr;
    f16x8 a0 = *(const f16x8*)&Ys[rowL * YP + lg * 8];
    f16x8 a1 = *(const f16x8*)&Ys[rowL * YP + 32 + lg * 8];
    f32x4 acc = {};
    acc = __builtin_amdgcn_mfma_f32_16x16x32_f16(a0, w0, acc, 0, 0, 0);
    acc = __builtin_amdgcn_mfma_f32_16x16x32_f16(a1, w1, acc, 0, 0, 0);
    int col = mt * 16 + lr;
#pragma unroll
    for (int i = 0; i < 4; ++i) {
        int nd = blockBase + rt * 16 + lg * 4 + i;
        if (nd < n)
            out[(size_t)nd * 32 + col] = __float2half_rn(acc[i] * dinv[nd]);
    }
}

// ---------------- agg3 (fp16 gather, 1 line/row) + MLP head ----------------
__global__ __launch_bounds__(256) void agg3_mlp_h(
    const __half* __restrict__ s, const int* __restrict__ offs,
    const int* __restrict__ csr, const float* __restrict__ dinv,
    const float* __restrict__ bg,
    const float* __restrict__ Wl1, const float* __restrict__ bl1,
    const float* __restrict__ Wl2, const float* __restrict__ bl2,
    const float* __restrict__ Wl3, const float* __restrict__ bl3,
    float* __restrict__ out, int n) {
    constexpr int MH = 25, SH = 32, LPN = 4;
    __shared__ float W1s[625], W2s[250], W3s[10], b1s[25], b2s[10];
    __shared__ float accs[64 * 26];
    __shared__ float b3s;

    for (int i = threadIdx.x; i < 625; i += 256) W1s[i] = Wl1[i];
    for (int i = threadIdx.x; i < 250; i += 256) W2s[i] = Wl2[i];
    if (threadIdx.x < 10) { W3s[threadIdx.x] = Wl3[threadIdx.x]; b2s[threadIdx.x] = bl2[threadIdx.x]; }
    if (threadIdx.x < 25) b1s[threadIdx.x] = bl1[threadIdx.x];
    if (threadIdx.x == 0) b3s = bl3[0];

    int lane = threadIdx.x % LPN;
    int nl   = threadIdx.x / LPN;
    int node = blockIdx.x * 64 + nl;
    int f0 = lane * 8;

    if (node < n && f0 < MH) {
        float dv = dinv[node];
        float4 z = make_float4(0.f, 0.f, 0.f, 0.f);
        float4 a00 = z, a01 = z, a10 = z, a11 = z, a20 = z, a21 = z, a30 = z, a31 = z;
        {
            H8 sv = *(const H8*)&s[(size_t)node * SH + f0];
            acc_h8(a00, a01, sv, 1.0f);
        }
        int e0 = offs[node], e1 = offs[node + 1];
        int e = e0;
        for (; e + 4 <= e1; e += 4) {
            int i0 = csr[e], i1 = csr[e + 1], i2 = csr[e + 2], i3 = csr[e + 3];
            H8 v0 = *(const H8*)&s[(size_t)i0 * SH + f0];
            H8 v1 = *(const H8*)&s[(size_t)i1 * SH + f0];
            H8 v2 = *(const H8*)&s[(size_t)i2 * SH + f0];
            H8 v3 = *(const H8*)&s[(size_t)i3 * SH + f0];
            acc_h8(a00, a01, v0, 1.0f);
            acc_h8(a10, a11, v1, 1.0f);
            acc_h8(a20, a21, v2, 1.0f);
            acc_h8(a30, a31, v3, 1.0f);
        }
        for (; e < e1; ++e) {
            H8 v = *(const H8*)&s[(size_t)csr[e] * SH + f0];
            acc_h8(a00, a01, v, 1.0f);
        }
        float4 A0 = add4(add4(a00, a10), add4(a20, a30));
        float4 A1 = add4(add4(a01, a11), add4(a21, a31));
        float v[8] = {A0.x, A0.y, A0.z, A0.w, A1.x, A1.y, A1.z, A1.w};
#pragma unroll
        for (int i = 0; i < 8; ++i)
            if (f0 + i < MH)
                accs[nl * 26 + f0 + i] = fmaxf(dv * v[i] + bg[f0 + i], 0.0f);
    }
    __syncthreads();

    if (threadIdx.x < 64) {
        int nd = blockIdx.x * 64 + threadIdx.x;
        if (nd < n) {
            const float* xr = &accs[threadIdx.x * 26];
            float h1[25];
#pragma unroll
            for (int m = 0; m < 25; ++m) {
                float a = b1s[m];
#pragma unroll
                for (int k = 0; k < 25; ++k) a = fmaf(xr[k], W1s[k * 25 + m], a);
                h1[m] = fmaxf(a, 0.0f);
            }
            float h2[10];
#pragma unroll
            for (int m = 0; m < 10; ++m) {
                float a = b2s[m];
#pragma unroll
                for (int k = 0; k < 25; ++k) a = fmaf(h1[k], W2s[k * 10 + m], a);
                h2[m] = fmaxf(a, 0.0f);
            }
            float a = b3s;
#pragma unroll
            for (int k = 0; k < 10; ++k) a = fmaf(h2[k], W3s[k], a);
            out[nd] = fmaxf(a, 0.0f);
        }
    }
}

// ---------------- launch ----------------

extern "C" void kernel_launch(void* const* d_in, const int* in_sizes, int n_in,
                              void* d_out, int out_size, void* d_ws, size_t ws_size,
                              hipStream_t stream) {
    const float* x0  = (const float*)d_in[0];
    const float* W1  = (const float*)d_in[1];
    const float* b1  = (const float*)d_in[2];
    const float* W2  = (const float*)d_in[3];
    const float* b2  = (const float*)d_in[4];
    const float* W3  = (const float*)d_in[5];
    const float* b3  = (const float*)d_in[6];
    const float* Wl1 = (const float*)d_in[7];
    const float* bl1 = (const float*)d_in[8];
    const float* Wl2 = (const float*)d_in[9];
    const float* bl2 = (const float*)d_in[10];
    const float* Wl3 = (const float*)d_in[11];
    const float* bl3 = (const float*)d_in[12];
    const int*   edge = (const int*)d_in[13];

    int n  = in_sizes[0] / 64;      // 100000
    int ne = in_sizes[13] / 2;      // 1000000
    const int* esrc = edge;
    const int* edst = edge + ne;

    char* ws = (char*)d_ws;
    auto alloc = [&](size_t bytes) {
        char* p = ws;
        ws += (bytes + 255) & ~(size_t)255;
        return p;
    };
    int*    offs       = (int*)alloc((size_t)(n + 1) * 4);
    int*    bucketCur  = (int*)alloc(NBUCK * 4);
    int*    csr        = (int*)alloc((size_t)ne * 4);
    float*  dinv       = (float*)alloc((size_t)n * 4);
    __half* x0h        = (__half*)alloc((size_t)n * 64 * 2);   // fp16 s64h (cvt out, dinv-prescaled)
    __half* bufDh      = (__half*)alloc((size_t)n * 64 * 2);   // fp16 s64h (agg1gemm12 out)
    __half* bufCh      = (__half*)alloc((size_t)n * 32 * 2);   // fp16 s32h (agg2g3 out)
    __half* P1         = (__half*)alloc(7 * 2 * 64 * 8 * 2);   // packed W1 frags
    __half* P2         = (__half*)alloc(4 * 4 * 64 * 8 * 2);   // packed W2 frags
    __half* P3         = (__half*)alloc(2 * 2 * 64 * 8 * 2);   // packed W3 frags
    // pairs (6.3MB) aliases bufDh: consumed by bucket_csr_scan before agg1gemm12 writes it
    int*    pairs = (int*)bufDh;
    (void)ws_size; (void)n_in; (void)out_size;

    int nbuckets = (n + (1 << BSHIFT) - 1) >> BSHIFT;   // 196
    int nchunk   = (ne + 256 * EPT - 1) / (256 * EPT);  // 245

    // CSR + dinv + weight pack (memset + 2 dispatches)
    hipMemsetAsync(bucketCur, 0, NBUCK * 4, stream);
    partition_pack<<<nchunk + 1, 256, 0, stream>>>(
        esrc, edst, bucketCur, pairs, ne, nchunk, W1, W2, W3, P1, P2, P3);
    bucket_csr_scan<<<nbuckets, 256, 0, stream>>>(
        pairs, bucketCur, offs, dinv, csr, n, ne, nbuckets);

    // x0h = fp16(dinv * x0)
    cvt_scale_f32_f16<<<(n * 16 + 255) / 256, 256, 0, stream>>>(x0, dinv, x0h, n * 16);

    // agg1 + gemm1 + gemm2 fused: bufDh = fp16(dinv * (relu(agg(x0h)@W1+b1) @ W2))
    agg1gemm12<<<(n + 63) / 64, 256, 0, stream>>>(
        x0h, offs, csr, dinv, P1, b1, P2, bufDh, n);

    // agg2 + gemm3 fused: bufCh = fp16(dinv * (relu(dinv*agg(bufDh)+b2) @ W3)) s32h
    agg2g3<<<(n + 31) / 32, 256, 0, stream>>>(
        bufDh, offs, csr, dinv, b2, P3, bufCh, n);

    // agg3 + MLP head -> d_out
    agg3_mlp_h<<<(n + 63) / 64, 256, 0, stream>>>(
        bufCh, offs, csr, dinv, b3, Wl1, bl1, Wl2, bl2, Wl3, bl3, (float*)d_out, n);
}